// Round 12
// baseline (186.662 us; speedup 1.0000x reference)
//
#include <hip/hip_runtime.h>
#include <hip/hip_bf16.h>
#include <math.h>

// ---------------------------------------------------------------------------
// Problem constants
// ---------------------------------------------------------------------------
#define BATCH 2
#define HH 128
#define WW 128
#define CC 512
#define NH 4
#define HD 128
#define KS 7
#define RR 3
#define KK2 49
#define NSI 9

#define GM (BATCH*HH*WW)   // 32768
#define GK CC              // 512
#define GN (2*CC)          // 1024

#define NEG_HUGE (-1.0e30f)

typedef __attribute__((ext_vector_type(8))) short bf16x8;
typedef __attribute__((ext_vector_type(4))) float f32x4;

__device__ __forceinline__ float sout(float v) {   // clamp kills NaN/inf
    return fminf(fmaxf(v, -3.0e38f), 3.0e38f);
}
__device__ __forceinline__ float bflo(unsigned int u) {
    return __builtin_bit_cast(float, u << 16);
}
__device__ __forceinline__ float bfhi(unsigned int u) {
    return __builtin_bit_cast(float, u & 0xffff0000u);
}
__device__ __forceinline__ unsigned short f2bf(float f) {   // RNE
    unsigned int u = __builtin_bit_cast(unsigned int, f);
    u += 0x7fffu + ((u >> 16) & 1u);
    return (unsigned short)(u >> 16);
}

// async global->LDS, 16B per lane; LDS dest must be wave-uniform base.
__device__ __forceinline__ void gl_lds16(const unsigned short* g, unsigned short* l) {
    __builtin_amdgcn_global_load_lds(
        (const __attribute__((address_space(1))) unsigned int*)g,
        (__attribute__((address_space(3))) unsigned int*)l, 16, 0, 0);
}

// ---------------------------------------------------------------------------
// Prep kernel: merged xcast (bid<8192) + wtrans (bid>=8192).
// ---------------------------------------------------------------------------
__global__ __launch_bounds__(256) void prep(const float* __restrict__ x,
                                            unsigned short* __restrict__ xb,
                                            const float* __restrict__ W,
                                            unsigned short* __restrict__ Wt) {
    int bid = blockIdx.x;
    if (bid < 8192) {
        int t = bid * 256 + threadIdx.x;           // 0..2,097,151
        const float4* s = (const float4*)(x + (size_t)t * 8);
        float4 v0 = s[0], v1 = s[1];
        bf16x8 pk;
        pk[0] = (short)f2bf(v0.x); pk[1] = (short)f2bf(v0.y);
        pk[2] = (short)f2bf(v0.z); pk[3] = (short)f2bf(v0.w);
        pk[4] = (short)f2bf(v1.x); pk[5] = (short)f2bf(v1.y);
        pk[6] = (short)f2bf(v1.z); pk[7] = (short)f2bf(v1.w);
        *(bf16x8*)(xb + (size_t)t * 8) = pk;
    } else {
        int t = (bid - 8192) * 256 + threadIdx.x;  // 0..524287
        int n = t >> 9, k = t & 511;
        Wt[(size_t)n * GK + k] = f2bf(W[(size_t)k * GN + n]);
    }
}

// ---------------------------------------------------------------------------
// Kernel 1a: bf16 MFMA GEMM, global_load_lds staging, XCD-chunked blocks.
// ---------------------------------------------------------------------------
#define TBM 128
#define TBN 128
#define TBK 64

__global__ __launch_bounds__(256, 3) void qk_gemm_async(
        const unsigned short* __restrict__ xb,
        const unsigned short* __restrict__ Wt,
        const float* __restrict__ bias,
        unsigned short* __restrict__ Cout)
{
    __shared__ unsigned short As[TBM * TBK];
    __shared__ unsigned short Bs[TBN * TBK];

    const int bid = blockIdx.x;
    const int xcd = bid & 7, idx = bid >> 3;          // idx 0..255
    const int m0 = (xcd * 32 + (idx >> 3)) * TBM;     // A-chunk per XCD (4 MB)
    const int n0 = (idx & 7) * TBN;

    const int tid = threadIdx.x;
    const int lane = tid & 63;
    const int wid = tid >> 6;
    const int wr = wid >> 1, wc = wid & 1;

    f32x4 acc[4][4];
#pragma unroll
    for (int i = 0; i < 4; ++i)
#pragma unroll
        for (int j = 0; j < 4; ++j) acc[i][j] = (f32x4){0.f, 0.f, 0.f, 0.f};

    const int srow = lane >> 3;
    const int scol = (lane & 7) * 8;

    for (int k0 = 0; k0 < GK; k0 += TBK) {
#pragma unroll
        for (int i = 0; i < 4; ++i) {
            int chunk = wid * 4 + i;
            int row = chunk * 8 + srow;
            gl_lds16(xb + (size_t)(m0 + row) * GK + k0 + scol, &As[chunk * 512]);
            gl_lds16(Wt + (size_t)(n0 + row) * GK + k0 + scol, &Bs[chunk * 512]);
        }
        __syncthreads();

#pragma unroll
        for (int ks = 0; ks < 2; ++ks) {
            const int koff = ks * 32 + (lane >> 4) * 8;
            bf16x8 af[4], bfr[4];
#pragma unroll
            for (int i = 0; i < 4; ++i)
                af[i] = *(const bf16x8*)&As[(wr * 64 + i * 16 + (lane & 15)) * TBK + koff];
#pragma unroll
            for (int j = 0; j < 4; ++j)
                bfr[j] = *(const bf16x8*)&Bs[(wc * 64 + j * 16 + (lane & 15)) * TBK + koff];
#pragma unroll
            for (int i = 0; i < 4; ++i)
#pragma unroll
                for (int j = 0; j < 4; ++j)
                    acc[i][j] = __builtin_amdgcn_mfma_f32_16x16x32_bf16(
                        af[i], bfr[j], acc[i][j], 0, 0, 0);
        }
        __syncthreads();
    }

    const int colbase = n0 + wc * 64;
    float bias4[4];
#pragma unroll
    for (int j = 0; j < 4; ++j) bias4[j] = bias[colbase + j * 16 + (lane & 15)];
#pragma unroll
    for (int i = 0; i < 4; ++i)
#pragma unroll
        for (int j = 0; j < 4; ++j)
#pragma unroll
            for (int r = 0; r < 4; ++r) {
                int row = m0 + wr * 64 + i * 16 + (lane >> 4) * 4 + r;
                int col = colbase + j * 16 + (lane & 15);
                Cout[(size_t)row * GN + col] = f2bf(acc[i][j][r] + bias4[j]);
            }
}

// ---------------------------------------------------------------------------
// Kernel 1b (ws fallback): conversion-staging GEMM (round-6, known-good).
// ---------------------------------------------------------------------------
#define LDAB 72

__global__ __launch_bounds__(256) void qk_gemm_conv(
        const float* __restrict__ X,
        const unsigned short* __restrict__ Wt,
        const float* __restrict__ bias,
        unsigned short* __restrict__ Cout)
{
    __shared__ unsigned short As[TBM][LDAB];
    __shared__ unsigned short Bs[TBN][LDAB];

    const int m0 = blockIdx.x * TBM;
    const int n0 = blockIdx.y * TBN;
    const int tid = threadIdx.x;
    const int lane = tid & 63;
    const int wid = tid >> 6;
    const int wr = wid >> 1, wc = wid & 1;

    f32x4 acc[4][4];
#pragma unroll
    for (int i = 0; i < 4; ++i)
#pragma unroll
        for (int j = 0; j < 4; ++j) acc[i][j] = (f32x4){0.f, 0.f, 0.f, 0.f};

    const int srow = tid >> 1;
    const int shalf = (tid & 1) * 32;

    for (int k0 = 0; k0 < GK; k0 += TBK) {
        {
            const float* srcA = X + (size_t)(m0 + srow) * GK + k0 + shalf;
#pragma unroll
            for (int i = 0; i < 4; ++i) {
                float4 v0 = ((const float4*)srcA)[i * 2];
                float4 v1 = ((const float4*)srcA)[i * 2 + 1];
                bf16x8 pk;
                pk[0] = (short)f2bf(v0.x); pk[1] = (short)f2bf(v0.y);
                pk[2] = (short)f2bf(v0.z); pk[3] = (short)f2bf(v0.w);
                pk[4] = (short)f2bf(v1.x); pk[5] = (short)f2bf(v1.y);
                pk[6] = (short)f2bf(v1.z); pk[7] = (short)f2bf(v1.w);
                *(bf16x8*)&As[srow][shalf + i * 8] = pk;
            }
        }
        {
            const unsigned short* srcB = Wt + (size_t)(n0 + srow) * GK + k0 + shalf;
#pragma unroll
            for (int i = 0; i < 4; ++i)
                *(uint4*)&Bs[srow][shalf + i * 8] = ((const uint4*)srcB)[i];
        }
        __syncthreads();

#pragma unroll
        for (int ks = 0; ks < 2; ++ks) {
            const int koff = ks * 32 + (lane >> 4) * 8;
            bf16x8 af[4], bfr[4];
#pragma unroll
            for (int i = 0; i < 4; ++i)
                af[i] = *(const bf16x8*)&As[wr * 64 + i * 16 + (lane & 15)][koff];
#pragma unroll
            for (int j = 0; j < 4; ++j)
                bfr[j] = *(const bf16x8*)&Bs[wc * 64 + j * 16 + (lane & 15)][koff];
#pragma unroll
            for (int i = 0; i < 4; ++i)
#pragma unroll
                for (int j = 0; j < 4; ++j)
                    acc[i][j] = __builtin_amdgcn_mfma_f32_16x16x32_bf16(
                        af[i], bfr[j], acc[i][j], 0, 0, 0);
        }
        __syncthreads();
    }

    const int colbase = n0 + wc * 64;
    float bias4[4];
#pragma unroll
    for (int j = 0; j < 4; ++j) bias4[j] = bias[colbase + j * 16 + (lane & 15)];
#pragma unroll
    for (int i = 0; i < 4; ++i)
#pragma unroll
        for (int j = 0; j < 4; ++j)
#pragma unroll
            for (int r = 0; r < 4; ++r) {
                int row = m0 + wr * 64 + i * 16 + (lane >> 4) * 4 + r;
                int col = colbase + j * 16 + (lane & 15);
                Cout[(size_t)row * GN + col] = f2bf(acc[i][j][r] + bias4[j]);
            }
}

// ---------------------------------------------------------------------------
// Kernel 2: attention scores via MFMA — split-K staging, bf16 transposed S.
// One block per (8x8 tile, head); 1D grid 2048, XCD-chunked swizzle.
// LDS = max(K-half 196x68 bf16 = 26656 B, St 208x68 bf16 = 28288 B) = 28288 B
// -> 4 blocks/CU (VGPR-capped via launch_bounds(256,4)).
// ---------------------------------------------------------------------------
#define HALO 14
#define NKROW 196
#define LKH 68           // K-half row stride (bf16): 64 + 4 pad (136 B)
#define LST 68           // St row stride (bf16): 64 + 4 pad
#define NSLOT 7          // ceil(196*8 / 256) 16B-slots per thread per half
#define NITER 13         // ceil(3136/256)
#define NITEMS (64*KK2)  // 3136

__global__ __launch_bounds__(256, 4) void attn_mfma(
        const unsigned short* __restrict__ qk,
        const float* __restrict__ sims,
        const int*   __restrict__ sinds,
        float* __restrict__ out)
{
    __shared__ __align__(16) unsigned char smem[28288];
    unsigned short* Ks = (unsigned short*)smem;   // [196][LKH] per half
    unsigned short* St = (unsigned short*)smem;   // [208][LST], aliases after

    // XCD-chunked swizzle (bijective: 2048 % 8 == 0)
    const int bid = blockIdx.x;
    const int spatial = (bid & 7) * 256 + (bid >> 3);
    const int tw = spatial & 15;
    const int th = (spatial >> 4) & 15;
    const int bg = spatial >> 8;
    const int b = bg >> 2, g = bg & 3;

    const int tid = threadIdx.x;
    const int lane = tid & 63;
    const int wm = tid >> 6;

    const int h0 = th * 8, w0 = tw * 8;
    const int hb = min(max(h0 - RR, 0), HH - KS);
    const int wb = min(max(w0 - RR, 0), WW - KS);

    // slot tables: per half, slot o covers K row (o>>3), 16B chunk (o&7)
    int jrow[NSLOT], ccol[NSLOT];
    size_t gbase[NSLOT];
#pragma unroll
    for (int p = 0; p < NSLOT; ++p) {
        int o = tid + p * 256;                 // 0..1791
        int jj = o >> 3, c = o & 7;
        int jr = min(jj, NKROW - 1);           // tail dups benign
        int hj = min(hb + jr / HALO, HH - 1);
        int wj = min(wb + jr % HALO, WW - 1);
        gbase[p] = ((size_t)((b * HH + hj) * WW + wj)) * GN + CC + g * HD + c * 8;
        jrow[p] = jr; ccol[p] = c;
    }

    const int pl_q = wm * 16 + (lane & 15);
    const size_t qrow = ((size_t)(b * HH + h0 + (pl_q >> 3)) * WW + w0 + (pl_q & 7)) * GN;
    const int kof8 = (lane >> 4) * 8;

    f32x4 svals[NITER];
#pragma unroll
    for (int nt = 0; nt < NITER; ++nt) svals[nt] = (f32x4){0.f, 0.f, 0.f, 0.f};

#pragma unroll
    for (int half = 0; half < 2; ++half) {
        // ---- stage this half's K (64 dims) ----
        uint4 kb[NSLOT];
#pragma unroll
        for (int p = 0; p < NSLOT; ++p)
            kb[p] = *(const uint4*)(qk + gbase[p] + half * 64);
#pragma unroll
        for (int p = 0; p < NSLOT; ++p)
            *(uint4*)&Ks[jrow[p] * LKH + ccol[p] * 8] = kb[p];
        __syncthreads();

        // ---- Q fragments for this half ----
        bf16x8 aq0 = *(const bf16x8*)(qk + qrow + g * HD + half * 64 + kof8);
        bf16x8 aq1 = *(const bf16x8*)(qk + qrow + g * HD + half * 64 + 32 + kof8);

        // ---- MFMA accumulate ----
        __builtin_amdgcn_s_setprio(1);
#pragma unroll
        for (int nt = 0; nt < NITER; ++nt) {
            int rB = min(nt * 16 + (lane & 15), NKROW - 1);
            bf16x8 bk0 = *(const bf16x8*)&Ks[rB * LKH + kof8];
            bf16x8 bk1 = *(const bf16x8*)&Ks[rB * LKH + 32 + kof8];
            svals[nt] = __builtin_amdgcn_mfma_f32_16x16x32_bf16(aq0, bk0, svals[nt], 0, 0, 0);
            svals[nt] = __builtin_amdgcn_mfma_f32_16x16x32_bf16(aq1, bk1, svals[nt], 0, 0, 0);
        }
        __builtin_amdgcn_s_setprio(0);
        __syncthreads();    // K reads done; safe to restage / alias St
    }

    // ---- St[j][pl] bf16: r=0..3 are consecutive cols -> one 8B write/nt ----
    const int qrbase = wm * 16 + (lane >> 4) * 4;
#pragma unroll
    for (int nt = 0; nt < NITER; ++nt) {
        unsigned int lo = (unsigned int)f2bf(svals[nt][0]) |
                          ((unsigned int)f2bf(svals[nt][1]) << 16);
        unsigned int hi = (unsigned int)f2bf(svals[nt][2]) |
                          ((unsigned int)f2bf(svals[nt][3]) << 16);
        uint2 pk; pk.x = lo; pk.y = hi;
        *(uint2*)&St[(nt * 16 + (lane & 15)) * LST + qrbase] = pk;
    }
    __syncthreads();

    // ---- readout + logp + 9 nontemporal writes per item ----
    const size_t plane = (size_t)HH * WW * KK2;
#pragma unroll
    for (int rr = 0; rr < NITER; ++rr) {
        int it = tid + rr * 256;
        if (it < NITEMS) {
            int pl = it / KK2, ki = it % KK2;
            int h = h0 + (pl >> 3), w = w0 + (pl & 7);
            int dh = ki / KS, dw = ki % KS;
            int hj = min(max(h - RR, 0), HH - KS) + dh;
            int wj = min(max(w - RR, 0), WW - KS) + dw;
            int j = (hj - hb) * HALO + (wj - wb);
            float dot = bflo((unsigned int)St[j * LST + pl]);
            int pix = (b * HH + h) * WW + w;
            int pj  = (b * HH + hj) * WW + wj;

            int sid[NSI], sjd[NSI]; float sjm[NSI];
            const int*   sip = sinds + (size_t)pix * NSI;
            const int*   sjp = sinds + (size_t)pj * NSI;
            const float* smp = sims + (size_t)pj * NSI;
#pragma unroll
            for (int m = 0; m < NSI; ++m) { sid[m] = sip[m]; sjd[m] = sjp[m]; sjm[m] = smp[m]; }

            size_t inner = (size_t)(h * WW + w) * KK2 + ki;
#pragma unroll
            for (int si = 0; si < NSI; ++si) {
                float p = 0.f;
#pragma unroll
                for (int m = 0; m < NSI; ++m) p += (sjd[m] == sid[si]) ? sjm[m] : 0.f;
                float lp = (p > 0.f) ? __logf(fmaxf(p, 1e-30f)) : NEG_HUGE;
                __builtin_nontemporal_store(sout(dot + lp),
                    &out[((size_t)((b * NH + g) * NSI + si)) * plane + inner]);
            }
        }
    }
}

// ---------------------------------------------------------------------------
// Zero-workspace fallback (round-5 fused VALU path).
// ---------------------------------------------------------------------------
#define FT 8
#define FH 14
#define FNP (FT*FT)
#define FNJ (FH*FH)
#define FDH 64
#define KPAD 68
#define FNITEM (FNP*KK2)
#define FNR 13

__global__ __launch_bounds__(256) void fused_attn(
        const float* __restrict__ x, const float* __restrict__ sims,
        const int* __restrict__ sinds, const float* __restrict__ Wm,
        const float* __restrict__ bias, float* __restrict__ out)
{
    __shared__ unsigned short kt[FNJ][KPAD];
    __shared__ unsigned short qt[FNP][KPAD];

    const int tw = blockIdx.x, th = blockIdx.y;
    const int b = blockIdx.z >> 2, g = blockIdx.z & 3;
    const int tid = threadIdx.x;
    const int hb = min(max(th * FT - RR, 0), HH - KS);
    const int wb = min(max(tw * FT - RR, 0), WW - KS);

    float dacc[FNR];
#pragma unroll
    for (int r = 0; r < FNR; ++r) dacc[r] = 0.f;

    for (int ph = 0; ph < 2; ++ph) {
        const int kcol0 = CC + g * HD + ph * FDH;
        const int qcol0 = g * HD + ph * FDH;

        for (int o = tid; o < FNJ * FDH; o += 256) {
            int j = o >> 6, dd = o & 63;
            int hj = min(hb + j / FH, HH - 1), wj = min(wb + j % FH, WW - 1);
            const float* xr = x + ((size_t)(b * HH + hj) * WW + wj) * CC;
            int col = kcol0 + dd;
            float acc = bias[col];
            for (int c = 0; c < CC; c += 4) {
                float4 xv = *(const float4*)(xr + c);
                acc += xv.x * Wm[(size_t)c * GN + col]
                     + xv.y * Wm[(size_t)(c + 1) * GN + col]
                     + xv.z * Wm[(size_t)(c + 2) * GN + col]
                     + xv.w * Wm[(size_t)(c + 3) * GN + col];
            }
            kt[j][dd] = f2bf(acc);
        }
        for (int o = tid; o < FNP * FDH; o += 256) {
            int i = o >> 6, dd = o & 63;
            int h = th * FT + (i >> 3), w = tw * FT + (i & 7);
            const float* xr = x + ((size_t)(b * HH + h) * WW + w) * CC;
            int col = qcol0 + dd;
            float acc = bias[col];
            for (int c = 0; c < CC; c += 4) {
                float4 xv = *(const float4*)(xr + c);
                acc += xv.x * Wm[(size_t)c * GN + col]
                     + xv.y * Wm[(size_t)(c + 1) * GN + col]
                     + xv.z * Wm[(size_t)(c + 2) * GN + col]
                     + xv.w * Wm[(size_t)(c + 3) * GN + col];
            }
            qt[i][dd] = f2bf(acc);
        }
        __syncthreads();

#pragma unroll
        for (int r = 0; r < FNR; ++r) {
            int it = tid + r * 256;
            if (it < FNITEM) {
                int pl = it / KK2, ki = it % KK2;
                int h = th * FT + (pl >> 3), w = tw * FT + (pl & 7);
                int dh = ki / KS, dw = ki % KS;
                int hj = min(max(h - RR, 0), HH - KS) + dh;
                int wj = min(max(w - RR, 0), WW - KS) + dw;
                int j = (hj - hb) * FH + (wj - wb);
                const unsigned int* qr = (const unsigned int*)&qt[pl][0];
                const unsigned int* kr = (const unsigned int*)&kt[j][0];
                float a = 0.f;
#pragma unroll 8
                for (int d = 0; d < FDH / 2; ++d) {
                    unsigned int qv = qr[d], kv = kr[d];
                    a += bflo(qv) * bflo(kv) + bfhi(qv) * bfhi(kv);
                }
                dacc[r] += a;
            }
        }
        __syncthreads();
    }

    const size_t plane = (size_t)HH * WW * KK2;
#pragma unroll
    for (int r = 0; r < FNR; ++r) {
        int it = tid + r * 256;
        if (it < FNITEM) {
            int pl = it / KK2, ki = it % KK2;
            int h = th * FT + (pl >> 3), w = tw * FT + (pl & 7);
            int dh = ki / KS, dw = ki % KS;
            int hj = min(max(h - RR, 0), HH - KS) + dh;
            int wj = min(max(w - RR, 0), WW - KS) + dw;
            int pix = (b * HH + h) * WW + w;
            int pj  = (b * HH + hj) * WW + wj;

            int sid[NSI], sjd[NSI]; float sjm[NSI];
            const int*   sip = sinds + (size_t)pix * NSI;
            const int*   sjp = sinds + (size_t)pj * NSI;
            const float* smp = sims + (size_t)pj * NSI;
#pragma unroll
            for (int m = 0; m < NSI; ++m) { sid[m] = sip[m]; sjd[m] = sjp[m]; sjm[m] = smp[m]; }

            const size_t inner = (size_t)(h * WW + w) * KK2 + ki;
#pragma unroll
            for (int si = 0; si < NSI; ++si) {
                float p = 0.f;
#pragma unroll
                for (int m = 0; m < NSI; ++m) p += (sjd[m] == sid[si]) ? sjm[m] : 0.f;
                float lp = (p > 0.f) ? __logf(fmaxf(p, 1e-30f)) : NEG_HUGE;
                out[((size_t)((b * NH + g) * NSI + si)) * plane + inner] =
                    sout(dacc[r] + lp);
            }
        }
    }
}

// ---------------------------------------------------------------------------
extern "C" void kernel_launch(void* const* d_in, const int* in_sizes, int n_in,
                              void* d_out, int out_size, void* d_ws, size_t ws_size,
                              hipStream_t stream) {
    const float* x     = (const float*)d_in[0];
    const float* sims  = (const float*)d_in[1];
    const int*   sinds = (const int*)d_in[2];
    const float* W_qk  = (const float*)d_in[3];
    const float* b_qk  = (const float*)d_in[4];
    float* out = (float*)d_out;

    const size_t qk_bytes = (size_t)GM * GN * sizeof(unsigned short);
    const size_t wt_bytes = (size_t)GN * GK * sizeof(unsigned short);
    const size_t xb_bytes = (size_t)GM * GK * sizeof(unsigned short);

    if (ws_size >= qk_bytes + wt_bytes + xb_bytes) {
        unsigned short* qk = (unsigned short*)d_ws;
        unsigned short* Wt = (unsigned short*)((char*)d_ws + qk_bytes);
        unsigned short* xb = (unsigned short*)((char*)d_ws + qk_bytes + wt_bytes);

        prep<<<8192 + 2048, 256, 0, stream>>>(x, xb, W_qk, Wt);
        qk_gemm_async<<<2048, 256, 0, stream>>>(xb, Wt, b_qk, qk);
        attn_mfma<<<2048, 256, 0, stream>>>(qk, sims, sinds, out);
    } else if (ws_size >= qk_bytes + wt_bytes) {
        unsigned short* qk = (unsigned short*)d_ws;
        unsigned short* Wt = (unsigned short*)((char*)d_ws + qk_bytes);

        prep<<<8192 + 2048, 256, 0, stream>>>(nullptr, nullptr, W_qk, Wt);  // unused xcast half guarded below
        dim3 ggrid(GM / TBM, GN / TBN);
        qk_gemm_conv<<<ggrid, 256, 0, stream>>>(x, Wt, b_qk, qk);
        attn_mfma<<<2048, 256, 0, stream>>>(qk, sims, sinds, out);
    } else {
        dim3 fgrid(WW / FT, HH / FT, BATCH * NH);
        fused_attn<<<fgrid, 256, 0, stream>>>(x, sims, sinds, W_qk, b_qk, out);
    }
}

// Round 13
// 164.525 us; speedup vs baseline: 1.1346x; 1.1346x over previous
//
#include <hip/hip_runtime.h>
#include <hip/hip_bf16.h>
#include <math.h>

// ---------------------------------------------------------------------------
// Problem constants
// ---------------------------------------------------------------------------
#define BATCH 2
#define HH 128
#define WW 128
#define CC 512
#define NH 4
#define HD 128
#define KS 7
#define RR 3
#define KK2 49
#define NSI 9

#define GM (BATCH*HH*WW)   // 32768
#define GK CC              // 512
#define GN (2*CC)          // 1024

#define NEG_HUGE (-1.0e30f)

typedef __attribute__((ext_vector_type(8))) short bf16x8;
typedef __attribute__((ext_vector_type(4))) float f32x4;

__device__ __forceinline__ float sout(float v) {   // clamp kills NaN/inf
    return fminf(fmaxf(v, -3.0e38f), 3.0e38f);
}
__device__ __forceinline__ float bflo(unsigned int u) {
    return __builtin_bit_cast(float, u << 16);
}
__device__ __forceinline__ float bfhi(unsigned int u) {
    return __builtin_bit_cast(float, u & 0xffff0000u);
}
__device__ __forceinline__ unsigned short f2bf(float f) {   // RNE
    unsigned int u = __builtin_bit_cast(unsigned int, f);
    u += 0x7fffu + ((u >> 16) & 1u);
    return (unsigned short)(u >> 16);
}

// async global->LDS, 16B per lane; LDS dest must be wave-uniform base.
__device__ __forceinline__ void gl_lds16(const unsigned short* g, unsigned short* l) {
    __builtin_amdgcn_global_load_lds(
        (const __attribute__((address_space(1))) unsigned int*)g,
        (__attribute__((address_space(3))) unsigned int*)l, 16, 0, 0);
}

// ---------------------------------------------------------------------------
// Prep kernel: merged xcast (bid < nxc) + wtrans (bid >= nxc).
// nxc = 0 disables the xcast half (middle ws path).
// ---------------------------------------------------------------------------
__global__ __launch_bounds__(256) void prep(const float* __restrict__ x,
                                            unsigned short* __restrict__ xb,
                                            const float* __restrict__ W,
                                            unsigned short* __restrict__ Wt,
                                            int nxc) {
    int bid = blockIdx.x;
    if (bid < nxc) {
        int t = bid * 256 + threadIdx.x;           // 0..2,097,151
        const float4* s = (const float4*)(x + (size_t)t * 8);
        float4 v0 = s[0], v1 = s[1];
        bf16x8 pk;
        pk[0] = (short)f2bf(v0.x); pk[1] = (short)f2bf(v0.y);
        pk[2] = (short)f2bf(v0.z); pk[3] = (short)f2bf(v0.w);
        pk[4] = (short)f2bf(v1.x); pk[5] = (short)f2bf(v1.y);
        pk[6] = (short)f2bf(v1.z); pk[7] = (short)f2bf(v1.w);
        *(bf16x8*)(xb + (size_t)t * 8) = pk;
    } else {
        int t = (bid - nxc) * 256 + threadIdx.x;   // 0..524287
        int n = t >> 9, k = t & 511;
        Wt[(size_t)n * GK + k] = f2bf(W[(size_t)k * GN + n]);
    }
}

// ---------------------------------------------------------------------------
// Kernel 1a: bf16 MFMA GEMM, global_load_lds staging, XCD-chunked blocks.
// ---------------------------------------------------------------------------
#define TBM 128
#define TBN 128
#define TBK 64

__global__ __launch_bounds__(256, 3) void qk_gemm_async(
        const unsigned short* __restrict__ xb,
        const unsigned short* __restrict__ Wt,
        const float* __restrict__ bias,
        unsigned short* __restrict__ Cout)
{
    __shared__ unsigned short As[TBM * TBK];
    __shared__ unsigned short Bs[TBN * TBK];

    const int bid = blockIdx.x;
    const int xcd = bid & 7, idx = bid >> 3;          // idx 0..255
    const int m0 = (xcd * 32 + (idx >> 3)) * TBM;     // A-chunk per XCD (4 MB)
    const int n0 = (idx & 7) * TBN;

    const int tid = threadIdx.x;
    const int lane = tid & 63;
    const int wid = tid >> 6;
    const int wr = wid >> 1, wc = wid & 1;

    f32x4 acc[4][4];
#pragma unroll
    for (int i = 0; i < 4; ++i)
#pragma unroll
        for (int j = 0; j < 4; ++j) acc[i][j] = (f32x4){0.f, 0.f, 0.f, 0.f};

    const int srow = lane >> 3;
    const int scol = (lane & 7) * 8;

    for (int k0 = 0; k0 < GK; k0 += TBK) {
#pragma unroll
        for (int i = 0; i < 4; ++i) {
            int chunk = wid * 4 + i;
            int row = chunk * 8 + srow;
            gl_lds16(xb + (size_t)(m0 + row) * GK + k0 + scol, &As[chunk * 512]);
            gl_lds16(Wt + (size_t)(n0 + row) * GK + k0 + scol, &Bs[chunk * 512]);
        }
        __syncthreads();

#pragma unroll
        for (int ks = 0; ks < 2; ++ks) {
            const int koff = ks * 32 + (lane >> 4) * 8;
            bf16x8 af[4], bfr[4];
#pragma unroll
            for (int i = 0; i < 4; ++i)
                af[i] = *(const bf16x8*)&As[(wr * 64 + i * 16 + (lane & 15)) * TBK + koff];
#pragma unroll
            for (int j = 0; j < 4; ++j)
                bfr[j] = *(const bf16x8*)&Bs[(wc * 64 + j * 16 + (lane & 15)) * TBK + koff];
#pragma unroll
            for (int i = 0; i < 4; ++i)
#pragma unroll
                for (int j = 0; j < 4; ++j)
                    acc[i][j] = __builtin_amdgcn_mfma_f32_16x16x32_bf16(
                        af[i], bfr[j], acc[i][j], 0, 0, 0);
        }
        __syncthreads();
    }

    const int colbase = n0 + wc * 64;
    float bias4[4];
#pragma unroll
    for (int j = 0; j < 4; ++j) bias4[j] = bias[colbase + j * 16 + (lane & 15)];
#pragma unroll
    for (int i = 0; i < 4; ++i)
#pragma unroll
        for (int j = 0; j < 4; ++j)
#pragma unroll
            for (int r = 0; r < 4; ++r) {
                int row = m0 + wr * 64 + i * 16 + (lane >> 4) * 4 + r;
                int col = colbase + j * 16 + (lane & 15);
                Cout[(size_t)row * GN + col] = f2bf(acc[i][j][r] + bias4[j]);
            }
}

// ---------------------------------------------------------------------------
// Kernel 1b (ws fallback): conversion-staging GEMM (round-6, known-good).
// ---------------------------------------------------------------------------
#define LDAB 72

__global__ __launch_bounds__(256) void qk_gemm_conv(
        const float* __restrict__ X,
        const unsigned short* __restrict__ Wt,
        const float* __restrict__ bias,
        unsigned short* __restrict__ Cout)
{
    __shared__ unsigned short As[TBM][LDAB];
    __shared__ unsigned short Bs[TBN][LDAB];

    const int m0 = blockIdx.x * TBM;
    const int n0 = blockIdx.y * TBN;
    const int tid = threadIdx.x;
    const int lane = tid & 63;
    const int wid = tid >> 6;
    const int wr = wid >> 1, wc = wid & 1;

    f32x4 acc[4][4];
#pragma unroll
    for (int i = 0; i < 4; ++i)
#pragma unroll
        for (int j = 0; j < 4; ++j) acc[i][j] = (f32x4){0.f, 0.f, 0.f, 0.f};

    const int srow = tid >> 1;
    const int shalf = (tid & 1) * 32;

    for (int k0 = 0; k0 < GK; k0 += TBK) {
        {
            const float* srcA = X + (size_t)(m0 + srow) * GK + k0 + shalf;
#pragma unroll
            for (int i = 0; i < 4; ++i) {
                float4 v0 = ((const float4*)srcA)[i * 2];
                float4 v1 = ((const float4*)srcA)[i * 2 + 1];
                bf16x8 pk;
                pk[0] = (short)f2bf(v0.x); pk[1] = (short)f2bf(v0.y);
                pk[2] = (short)f2bf(v0.z); pk[3] = (short)f2bf(v0.w);
                pk[4] = (short)f2bf(v1.x); pk[5] = (short)f2bf(v1.y);
                pk[6] = (short)f2bf(v1.z); pk[7] = (short)f2bf(v1.w);
                *(bf16x8*)&As[srow][shalf + i * 8] = pk;
            }
        }
        {
            const unsigned short* srcB = Wt + (size_t)(n0 + srow) * GK + k0 + shalf;
#pragma unroll
            for (int i = 0; i < 4; ++i)
                *(uint4*)&Bs[srow][shalf + i * 8] = ((const uint4*)srcB)[i];
        }
        __syncthreads();

#pragma unroll
        for (int ks = 0; ks < 2; ++ks) {
            const int koff = ks * 32 + (lane >> 4) * 8;
            bf16x8 af[4], bfr[4];
#pragma unroll
            for (int i = 0; i < 4; ++i)
                af[i] = *(const bf16x8*)&As[wr * 64 + i * 16 + (lane & 15)][koff];
#pragma unroll
            for (int j = 0; j < 4; ++j)
                bfr[j] = *(const bf16x8*)&Bs[wc * 64 + j * 16 + (lane & 15)][koff];
#pragma unroll
            for (int i = 0; i < 4; ++i)
#pragma unroll
                for (int j = 0; j < 4; ++j)
                    acc[i][j] = __builtin_amdgcn_mfma_f32_16x16x32_bf16(
                        af[i], bfr[j], acc[i][j], 0, 0, 0);
        }
        __syncthreads();
    }

    const int colbase = n0 + wc * 64;
    float bias4[4];
#pragma unroll
    for (int j = 0; j < 4; ++j) bias4[j] = bias[colbase + j * 16 + (lane & 15)];
#pragma unroll
    for (int i = 0; i < 4; ++i)
#pragma unroll
        for (int j = 0; j < 4; ++j)
#pragma unroll
            for (int r = 0; r < 4; ++r) {
                int row = m0 + wr * 64 + i * 16 + (lane >> 4) * 4 + r;
                int col = colbase + j * 16 + (lane & 15);
                Cout[(size_t)row * GN + col] = f2bf(acc[i][j][r] + bias4[j]);
            }
}

// ---------------------------------------------------------------------------
// Kernel 2: attention scores via MFMA — ROUND-11 STRUCTURE RESTORED.
// One block per (8x8 tile, head); 1D grid 2048, XCD-chunked swizzle;
// K halo 196 rows (LQK=136 pad); S[64][204] f32 aliases K; NT out stores.
// ---------------------------------------------------------------------------
#define HALO 14
#define NKROW 196
#define LQK 136          // 128 + 8 pad (272 B rows)
#define LSS 204          // S f32 row stride: (4*204)%32 = 16 -> free 2-way
#define NIT 13
#define NITEMS (64*KK2)  // 3136

__global__ __launch_bounds__(256, 3) void attn_mfma(
        const unsigned short* __restrict__ qk,
        const float* __restrict__ sims,
        const int*   __restrict__ sinds,
        float* __restrict__ out)
{
    __shared__ __align__(16) unsigned char smem[53312];   // K 53312 B; S 52224 B
    unsigned short* Ks = (unsigned short*)smem;
    float* Ss = (float*)smem;

    // XCD-chunked swizzle (bijective: 2048 % 8 == 0): xcd = bid&7 gets one
    // full (b,g) plane of 256 tiles -> halo re-reads are same-L2.
    const int bid = blockIdx.x;
    const int spatial = (bid & 7) * 256 + (bid >> 3);
    const int tw = spatial & 15;
    const int th = (spatial >> 4) & 15;
    const int bg = spatial >> 8;          // 0..7
    const int b = bg >> 2, g = bg & 3;

    const int tid = threadIdx.x;
    const int lane = tid & 63;
    const int wm = tid >> 6;

    const int h0 = th * 8, w0 = tw * 8;
    const int hb = min(max(h0 - RR, 0), HH - KS);
    const int wb = min(max(w0 - RR, 0), WW - KS);

    // ---- stage K halo for head g: 13 slots (16B each) per thread ----
    uint4 kb[NIT];
    int jrow[NIT], ccol[NIT];
#pragma unroll
    for (int p = 0; p < NIT; ++p) {
        int o = tid + p * 256;                 // 0..3327
        int jj = o >> 4, c = o & 15;
        int jr = min(jj, NKROW - 1);           // tail dups: same data, benign
        int hj = min(hb + jr / HALO, HH - 1);
        int wj = min(wb + jr % HALO, WW - 1);
        kb[p] = *(const uint4*)(qk + ((size_t)((b * HH + hj) * WW + wj)) * GN
                                   + CC + g * HD + c * 8);
        jrow[p] = jr; ccol[p] = c;
    }

    // ---- Q fragments direct to registers ----
    const int pl_q = wm * 16 + (lane & 15);
    const size_t qrow = ((size_t)(b * HH + h0 + (pl_q >> 3)) * WW + w0 + (pl_q & 7)) * GN;
    const int kof8 = (lane >> 4) * 8;
    bf16x8 aq[4];
#pragma unroll
    for (int ks = 0; ks < 4; ++ks)
        aq[ks] = *(const bf16x8*)(qk + qrow + g * HD + ks * 32 + kof8);

#pragma unroll
    for (int p = 0; p < NIT; ++p)
        *(uint4*)&Ks[jrow[p] * LQK + ccol[p] * 8] = kb[p];
    __syncthreads();

    // ---- MFMA S[64][196+clamp] ----
    __builtin_amdgcn_s_setprio(1);
    f32x4 svals[NIT];
#pragma unroll
    for (int nt = 0; nt < NIT; ++nt) {
        int rB = min(nt * 16 + (lane & 15), NKROW - 1);   // tile 13 clamps
        f32x4 sacc = (f32x4){0.f, 0.f, 0.f, 0.f};
#pragma unroll
        for (int ks = 0; ks < 4; ++ks) {
            bf16x8 bk = *(const bf16x8*)&Ks[rB * LQK + ks * 32 + kof8];
            sacc = __builtin_amdgcn_mfma_f32_16x16x32_bf16(aq[ks], bk, sacc, 0, 0, 0);
        }
        svals[nt] = sacc;
    }
    __builtin_amdgcn_s_setprio(0);
    __syncthreads();       // K reads done; safe to alias S

    // ---- S -> LDS ----
#pragma unroll
    for (int nt = 0; nt < NIT; ++nt)
#pragma unroll
        for (int r = 0; r < 4; ++r) {
            int qr = wm * 16 + (lane >> 4) * 4 + r;
            Ss[qr * LSS + nt * 16 + (lane & 15)] = svals[nt][r];
        }
    __syncthreads();

    // ---- readout + logp + 9 nontemporal writes per item ----
    const size_t plane = (size_t)HH * WW * KK2;
#pragma unroll
    for (int rr = 0; rr < NIT; ++rr) {
        int it = tid + rr * 256;
        if (it < NITEMS) {
            int pl = it / KK2, ki = it % KK2;
            int h = h0 + (pl >> 3), w = w0 + (pl & 7);
            int dh = ki / KS, dw = ki % KS;
            int hj = min(max(h - RR, 0), HH - KS) + dh;
            int wj = min(max(w - RR, 0), WW - KS) + dw;
            int j = (hj - hb) * HALO + (wj - wb);
            float dot = Ss[pl * LSS + j];
            int pix = (b * HH + h) * WW + w;
            int pj  = (b * HH + hj) * WW + wj;

            int sid[NSI], sjd[NSI]; float sjm[NSI];
            const int*   sip = sinds + (size_t)pix * NSI;
            const int*   sjp = sinds + (size_t)pj * NSI;
            const float* smp = sims + (size_t)pj * NSI;
#pragma unroll
            for (int m = 0; m < NSI; ++m) { sid[m] = sip[m]; sjd[m] = sjp[m]; sjm[m] = smp[m]; }

            size_t inner = (size_t)(h * WW + w) * KK2 + ki;
#pragma unroll
            for (int si = 0; si < NSI; ++si) {
                float p = 0.f;
#pragma unroll
                for (int m = 0; m < NSI; ++m) p += (sjd[m] == sid[si]) ? sjm[m] : 0.f;
                float lp = (p > 0.f) ? __logf(fmaxf(p, 1e-30f)) : NEG_HUGE;
                __builtin_nontemporal_store(sout(dot + lp),
                    &out[((size_t)((b * NH + g) * NSI + si)) * plane + inner]);
            }
        }
    }
}

// ---------------------------------------------------------------------------
// Zero-workspace fallback (round-5 fused VALU path).
// ---------------------------------------------------------------------------
#define FT 8
#define FH 14
#define FNP (FT*FT)
#define FNJ (FH*FH)
#define FDH 64
#define KPAD 68
#define FNITEM (FNP*KK2)
#define FNR 13

__global__ __launch_bounds__(256) void fused_attn(
        const float* __restrict__ x, const float* __restrict__ sims,
        const int* __restrict__ sinds, const float* __restrict__ Wm,
        const float* __restrict__ bias, float* __restrict__ out)
{
    __shared__ unsigned short kt[FNJ][KPAD];
    __shared__ unsigned short qt[FNP][KPAD];

    const int tw = blockIdx.x, th = blockIdx.y;
    const int b = blockIdx.z >> 2, g = blockIdx.z & 3;
    const int tid = threadIdx.x;
    const int hb = min(max(th * FT - RR, 0), HH - KS);
    const int wb = min(max(tw * FT - RR, 0), WW - KS);

    float dacc[FNR];
#pragma unroll
    for (int r = 0; r < FNR; ++r) dacc[r] = 0.f;

    for (int ph = 0; ph < 2; ++ph) {
        const int kcol0 = CC + g * HD + ph * FDH;
        const int qcol0 = g * HD + ph * FDH;

        for (int o = tid; o < FNJ * FDH; o += 256) {
            int j = o >> 6, dd = o & 63;
            int hj = min(hb + j / FH, HH - 1), wj = min(wb + j % FH, WW - 1);
            const float* xr = x + ((size_t)(b * HH + hj) * WW + wj) * CC;
            int col = kcol0 + dd;
            float acc = bias[col];
            for (int c = 0; c < CC; c += 4) {
                float4 xv = *(const float4*)(xr + c);
                acc += xv.x * Wm[(size_t)c * GN + col]
                     + xv.y * Wm[(size_t)(c + 1) * GN + col]
                     + xv.z * Wm[(size_t)(c + 2) * GN + col]
                     + xv.w * Wm[(size_t)(c + 3) * GN + col];
            }
            kt[j][dd] = f2bf(acc);
        }
        for (int o = tid; o < FNP * FDH; o += 256) {
            int i = o >> 6, dd = o & 63;
            int h = th * FT + (i >> 3), w = tw * FT + (i & 7);
            const float* xr = x + ((size_t)(b * HH + h) * WW + w) * CC;
            int col = qcol0 + dd;
            float acc = bias[col];
            for (int c = 0; c < CC; c += 4) {
                float4 xv = *(const float4*)(xr + c);
                acc += xv.x * Wm[(size_t)c * GN + col]
                     + xv.y * Wm[(size_t)(c + 1) * GN + col]
                     + xv.z * Wm[(size_t)(c + 2) * GN + col]
                     + xv.w * Wm[(size_t)(c + 3) * GN + col];
            }
            qt[i][dd] = f2bf(acc);
        }
        __syncthreads();

#pragma unroll
        for (int r = 0; r < FNR; ++r) {
            int it = tid + r * 256;
            if (it < FNITEM) {
                int pl = it / KK2, ki = it % KK2;
                int h = th * FT + (pl >> 3), w = tw * FT + (pl & 7);
                int dh = ki / KS, dw = ki % KS;
                int hj = min(max(h - RR, 0), HH - KS) + dh;
                int wj = min(max(w - RR, 0), WW - KS) + dw;
                int j = (hj - hb) * FH + (wj - wb);
                const unsigned int* qr = (const unsigned int*)&qt[pl][0];
                const unsigned int* kr = (const unsigned int*)&kt[j][0];
                float a = 0.f;
#pragma unroll 8
                for (int d = 0; d < FDH / 2; ++d) {
                    unsigned int qv = qr[d], kv = kr[d];
                    a += bflo(qv) * bflo(kv) + bfhi(qv) * bfhi(kv);
                }
                dacc[r] += a;
            }
        }
        __syncthreads();
    }

    const size_t plane = (size_t)HH * WW * KK2;
#pragma unroll
    for (int r = 0; r < FNR; ++r) {
        int it = tid + r * 256;
        if (it < FNITEM) {
            int pl = it / KK2, ki = it % KK2;
            int h = th * FT + (pl >> 3), w = tw * FT + (pl & 7);
            int dh = ki / KS, dw = ki % KS;
            int hj = min(max(h - RR, 0), HH - KS) + dh;
            int wj = min(max(w - RR, 0), WW - KS) + dw;
            int pix = (b * HH + h) * WW + w;
            int pj  = (b * HH + hj) * WW + wj;

            int sid[NSI], sjd[NSI]; float sjm[NSI];
            const int*   sip = sinds + (size_t)pix * NSI;
            const int*   sjp = sinds + (size_t)pj * NSI;
            const float* smp = sims + (size_t)pj * NSI;
#pragma unroll
            for (int m = 0; m < NSI; ++m) { sid[m] = sip[m]; sjd[m] = sjp[m]; sjm[m] = smp[m]; }

            const size_t inner = (size_t)(h * WW + w) * KK2 + ki;
#pragma unroll
            for (int si = 0; si < NSI; ++si) {
                float p = 0.f;
#pragma unroll
                for (int m = 0; m < NSI; ++m) p += (sjd[m] == sid[si]) ? sjm[m] : 0.f;
                float lp = (p > 0.f) ? __logf(fmaxf(p, 1e-30f)) : NEG_HUGE;
                out[((size_t)((b * NH + g) * NSI + si)) * plane + inner] =
                    sout(dacc[r] + lp);
            }
        }
    }
}

// ---------------------------------------------------------------------------
extern "C" void kernel_launch(void* const* d_in, const int* in_sizes, int n_in,
                              void* d_out, int out_size, void* d_ws, size_t ws_size,
                              hipStream_t stream) {
    const float* x     = (const float*)d_in[0];
    const float* sims  = (const float*)d_in[1];
    const int*   sinds = (const int*)d_in[2];
    const float* W_qk  = (const float*)d_in[3];
    const float* b_qk  = (const float*)d_in[4];
    float* out = (float*)d_out;

    const size_t qk_bytes = (size_t)GM * GN * sizeof(unsigned short);
    const size_t wt_bytes = (size_t)GN * GK * sizeof(unsigned short);
    const size_t xb_bytes = (size_t)GM * GK * sizeof(unsigned short);

    if (ws_size >= qk_bytes + wt_bytes + xb_bytes) {
        unsigned short* qk = (unsigned short*)d_ws;
        unsigned short* Wt = (unsigned short*)((char*)d_ws + qk_bytes);
        unsigned short* xb = (unsigned short*)((char*)d_ws + qk_bytes + wt_bytes);

        prep<<<8192 + 2048, 256, 0, stream>>>(x, xb, W_qk, Wt, 8192);
        qk_gemm_async<<<2048, 256, 0, stream>>>(xb, Wt, b_qk, qk);
        attn_mfma<<<2048, 256, 0, stream>>>(qk, sims, sinds, out);
    } else if (ws_size >= qk_bytes + wt_bytes) {
        unsigned short* qk = (unsigned short*)d_ws;
        unsigned short* Wt = (unsigned short*)((char*)d_ws + qk_bytes);

        prep<<<2048, 256, 0, stream>>>(x, nullptr, W_qk, Wt, 0);   // wtrans only
        dim3 ggrid(GM / TBM, GN / TBN);
        qk_gemm_conv<<<ggrid, 256, 0, stream>>>(x, Wt, b_qk, qk);
        attn_mfma<<<2048, 256, 0, stream>>>(qk, sims, sinds, out);
    } else {
        dim3 fgrid(WW / FT, HH / FT, BATCH * NH);
        fused_attn<<<fgrid, 256, 0, stream>>>(x, sims, sinds, W_qk, b_qk, out);
    }
}

// Round 14
// 164.472 us; speedup vs baseline: 1.1349x; 1.0003x over previous
//
#include <hip/hip_runtime.h>
#include <hip/hip_bf16.h>
#include <math.h>

// ---------------------------------------------------------------------------
// Problem constants
// ---------------------------------------------------------------------------
#define BATCH 2
#define HH 128
#define WW 128
#define CC 512
#define NH 4
#define HD 128
#define KS 7
#define RR 3
#define KK2 49
#define NSI 9

#define GM (BATCH*HH*WW)   // 32768
#define GK CC              // 512
#define GN (2*CC)          // 1024
#define NPIX (BATCH*HH*WW)        // 32768
#define NITEM_ALL (NPIX*KK2)      // 1,605,632

#define NEG_HUGE (-1.0e30f)

typedef __attribute__((ext_vector_type(8))) short bf16x8;
typedef __attribute__((ext_vector_type(4))) float f32x4;

__device__ __forceinline__ float sout(float v) {   // clamp kills NaN/inf
    return fminf(fmaxf(v, -3.0e38f), 3.0e38f);
}
__device__ __forceinline__ float bflo(unsigned int u) {
    return __builtin_bit_cast(float, u << 16);
}
__device__ __forceinline__ float bfhi(unsigned int u) {
    return __builtin_bit_cast(float, u & 0xffff0000u);
}
__device__ __forceinline__ unsigned short f2bf(float f) {   // RNE
    unsigned int u = __builtin_bit_cast(unsigned int, f);
    u += 0x7fffu + ((u >> 16) & 1u);
    return (unsigned short)(u >> 16);
}

// async global->LDS, 16B per lane; LDS dest must be wave-uniform base.
__device__ __forceinline__ void gl_lds16(const unsigned short* g, unsigned short* l) {
    __builtin_amdgcn_global_load_lds(
        (const __attribute__((address_space(1))) unsigned int*)g,
        (__attribute__((address_space(3))) unsigned int*)l, 16, 0, 0);
}

// ---------------------------------------------------------------------------
// Prep kernel, three segments:
//   bid < nxc            : xcast  (x fp32 -> xb bf16, 8 elems/thread)
//   nxc <= bid < nxc+nwt : wtrans (W [512][1024] -> Wt [1024][512] bf16)
//   else                 : logp   (per (pixel,ki): 9 log-probs -> lpA/lpB bf16)
// ---------------------------------------------------------------------------
__global__ __launch_bounds__(256) void prep(const float* __restrict__ x,
                                            unsigned short* __restrict__ xb,
                                            const float* __restrict__ W,
                                            unsigned short* __restrict__ Wt,
                                            const float* __restrict__ sims,
                                            const int* __restrict__ sinds,
                                            uint4* __restrict__ lpA,
                                            unsigned short* __restrict__ lpB,
                                            int nxc, int nwt) {
    int bid = blockIdx.x;
    if (bid < nxc) {
        int t = bid * 256 + threadIdx.x;           // 0..2,097,151
        const float4* s = (const float4*)(x + (size_t)t * 8);
        float4 v0 = s[0], v1 = s[1];
        bf16x8 pk;
        pk[0] = (short)f2bf(v0.x); pk[1] = (short)f2bf(v0.y);
        pk[2] = (short)f2bf(v0.z); pk[3] = (short)f2bf(v0.w);
        pk[4] = (short)f2bf(v1.x); pk[5] = (short)f2bf(v1.y);
        pk[6] = (short)f2bf(v1.z); pk[7] = (short)f2bf(v1.w);
        *(bf16x8*)(xb + (size_t)t * 8) = pk;
    } else if (bid < nxc + nwt) {
        int t = (bid - nxc) * 256 + threadIdx.x;   // 0..524287
        int n = t >> 9, k = t & 511;
        Wt[(size_t)n * GK + k] = f2bf(W[(size_t)k * GN + n]);
    } else {
        int t = (bid - nxc - nwt) * 256 + threadIdx.x;   // 0..1,605,631
        if (t < NITEM_ALL) {
            int ki  = t % KK2;
            int pix = t / KK2;
            int w   = pix & (WW - 1);
            int tmp = pix >> 7;
            int h   = tmp & (HH - 1);
            int b   = tmp >> 7;
            int dh = ki / KS, dw = ki % KS;
            int hj = min(max(h - RR, 0), HH - KS) + dh;
            int wj = min(max(w - RR, 0), WW - KS) + dw;
            int pj = (b * HH + hj) * WW + wj;

            int sid[NSI], sjd[NSI]; float sjm[NSI];
            const int*   sip = sinds + (size_t)pix * NSI;
            const int*   sjp = sinds + (size_t)pj * NSI;
            const float* smp = sims + (size_t)pj * NSI;
#pragma unroll
            for (int m = 0; m < NSI; ++m) { sid[m] = sip[m]; sjd[m] = sjp[m]; sjm[m] = smp[m]; }

            unsigned short lb[NSI];
#pragma unroll
            for (int si = 0; si < NSI; ++si) {
                float p = 0.f;
#pragma unroll
                for (int m = 0; m < NSI; ++m) p += (sjd[m] == sid[si]) ? sjm[m] : 0.f;
                float lp = (p > 0.f) ? __logf(fmaxf(p, 1e-30f)) : NEG_HUGE;
                lb[si] = f2bf(lp);
            }
            uint4 va;
            va.x = (unsigned int)lb[0] | ((unsigned int)lb[1] << 16);
            va.y = (unsigned int)lb[2] | ((unsigned int)lb[3] << 16);
            va.z = (unsigned int)lb[4] | ((unsigned int)lb[5] << 16);
            va.w = (unsigned int)lb[6] | ((unsigned int)lb[7] << 16);
            lpA[t] = va;
            lpB[t] = lb[8];
        }
    }
}

// ---------------------------------------------------------------------------
// Kernel 1a: bf16 MFMA GEMM, global_load_lds staging, XCD-chunked blocks.
// ---------------------------------------------------------------------------
#define TBM 128
#define TBN 128
#define TBK 64

__global__ __launch_bounds__(256, 3) void qk_gemm_async(
        const unsigned short* __restrict__ xb,
        const unsigned short* __restrict__ Wt,
        const float* __restrict__ bias,
        unsigned short* __restrict__ Cout)
{
    __shared__ unsigned short As[TBM * TBK];
    __shared__ unsigned short Bs[TBN * TBK];

    const int bid = blockIdx.x;
    const int xcd = bid & 7, idx = bid >> 3;          // idx 0..255
    const int m0 = (xcd * 32 + (idx >> 3)) * TBM;     // A-chunk per XCD (4 MB)
    const int n0 = (idx & 7) * TBN;

    const int tid = threadIdx.x;
    const int lane = tid & 63;
    const int wid = tid >> 6;
    const int wr = wid >> 1, wc = wid & 1;

    f32x4 acc[4][4];
#pragma unroll
    for (int i = 0; i < 4; ++i)
#pragma unroll
        for (int j = 0; j < 4; ++j) acc[i][j] = (f32x4){0.f, 0.f, 0.f, 0.f};

    const int srow = lane >> 3;
    const int scol = (lane & 7) * 8;

    for (int k0 = 0; k0 < GK; k0 += TBK) {
#pragma unroll
        for (int i = 0; i < 4; ++i) {
            int chunk = wid * 4 + i;
            int row = chunk * 8 + srow;
            gl_lds16(xb + (size_t)(m0 + row) * GK + k0 + scol, &As[chunk * 512]);
            gl_lds16(Wt + (size_t)(n0 + row) * GK + k0 + scol, &Bs[chunk * 512]);
        }
        __syncthreads();

#pragma unroll
        for (int ks = 0; ks < 2; ++ks) {
            const int koff = ks * 32 + (lane >> 4) * 8;
            bf16x8 af[4], bfr[4];
#pragma unroll
            for (int i = 0; i < 4; ++i)
                af[i] = *(const bf16x8*)&As[(wr * 64 + i * 16 + (lane & 15)) * TBK + koff];
#pragma unroll
            for (int j = 0; j < 4; ++j)
                bfr[j] = *(const bf16x8*)&Bs[(wc * 64 + j * 16 + (lane & 15)) * TBK + koff];
#pragma unroll
            for (int i = 0; i < 4; ++i)
#pragma unroll
                for (int j = 0; j < 4; ++j)
                    acc[i][j] = __builtin_amdgcn_mfma_f32_16x16x32_bf16(
                        af[i], bfr[j], acc[i][j], 0, 0, 0);
        }
        __syncthreads();
    }

    const int colbase = n0 + wc * 64;
    float bias4[4];
#pragma unroll
    for (int j = 0; j < 4; ++j) bias4[j] = bias[colbase + j * 16 + (lane & 15)];
#pragma unroll
    for (int i = 0; i < 4; ++i)
#pragma unroll
        for (int j = 0; j < 4; ++j)
#pragma unroll
            for (int r = 0; r < 4; ++r) {
                int row = m0 + wr * 64 + i * 16 + (lane >> 4) * 4 + r;
                int col = colbase + j * 16 + (lane & 15);
                Cout[(size_t)row * GN + col] = f2bf(acc[i][j][r] + bias4[j]);
            }
}

// ---------------------------------------------------------------------------
// Kernel 1b (ws fallback): conversion-staging GEMM (round-6, known-good).
// ---------------------------------------------------------------------------
#define LDAB 72

__global__ __launch_bounds__(256) void qk_gemm_conv(
        const float* __restrict__ X,
        const unsigned short* __restrict__ Wt,
        const float* __restrict__ bias,
        unsigned short* __restrict__ Cout)
{
    __shared__ unsigned short As[TBM][LDAB];
    __shared__ unsigned short Bs[TBN][LDAB];

    const int m0 = blockIdx.x * TBM;
    const int n0 = blockIdx.y * TBN;
    const int tid = threadIdx.x;
    const int lane = tid & 63;
    const int wid = tid >> 6;
    const int wr = wid >> 1, wc = wid & 1;

    f32x4 acc[4][4];
#pragma unroll
    for (int i = 0; i < 4; ++i)
#pragma unroll
        for (int j = 0; j < 4; ++j) acc[i][j] = (f32x4){0.f, 0.f, 0.f, 0.f};

    const int srow = tid >> 1;
    const int shalf = (tid & 1) * 32;

    for (int k0 = 0; k0 < GK; k0 += TBK) {
        {
            const float* srcA = X + (size_t)(m0 + srow) * GK + k0 + shalf;
#pragma unroll
            for (int i = 0; i < 4; ++i) {
                float4 v0 = ((const float4*)srcA)[i * 2];
                float4 v1 = ((const float4*)srcA)[i * 2 + 1];
                bf16x8 pk;
                pk[0] = (short)f2bf(v0.x); pk[1] = (short)f2bf(v0.y);
                pk[2] = (short)f2bf(v0.z); pk[3] = (short)f2bf(v0.w);
                pk[4] = (short)f2bf(v1.x); pk[5] = (short)f2bf(v1.y);
                pk[6] = (short)f2bf(v1.z); pk[7] = (short)f2bf(v1.w);
                *(bf16x8*)&As[srow][shalf + i * 8] = pk;
            }
        }
        {
            const unsigned short* srcB = Wt + (size_t)(n0 + srow) * GK + k0 + shalf;
#pragma unroll
            for (int i = 0; i < 4; ++i)
                *(uint4*)&Bs[srow][shalf + i * 8] = ((const uint4*)srcB)[i];
        }
        __syncthreads();

#pragma unroll
        for (int ks = 0; ks < 2; ++ks) {
            const int koff = ks * 32 + (lane >> 4) * 8;
            bf16x8 af[4], bfr[4];
#pragma unroll
            for (int i = 0; i < 4; ++i)
                af[i] = *(const bf16x8*)&As[wr * 64 + i * 16 + (lane & 15)][koff];
#pragma unroll
            for (int j = 0; j < 4; ++j)
                bfr[j] = *(const bf16x8*)&Bs[wc * 64 + j * 16 + (lane & 15)][koff];
#pragma unroll
            for (int i = 0; i < 4; ++i)
#pragma unroll
                for (int j = 0; j < 4; ++j)
                    acc[i][j] = __builtin_amdgcn_mfma_f32_16x16x32_bf16(
                        af[i], bfr[j], acc[i][j], 0, 0, 0);
        }
        __syncthreads();
    }

    const int colbase = n0 + wc * 64;
    float bias4[4];
#pragma unroll
    for (int j = 0; j < 4; ++j) bias4[j] = bias[colbase + j * 16 + (lane & 15)];
#pragma unroll
    for (int i = 0; i < 4; ++i)
#pragma unroll
        for (int j = 0; j < 4; ++j)
#pragma unroll
            for (int r = 0; r < 4; ++r) {
                int row = m0 + wr * 64 + i * 16 + (lane >> 4) * 4 + r;
                int col = colbase + j * 16 + (lane & 15);
                Cout[(size_t)row * GN + col] = f2bf(acc[i][j][r] + bias4[j]);
            }
}

// ---------------------------------------------------------------------------
// Kernel 2 (main path): attention scores via MFMA, logp PRELOADED.
// Round-11 structure; epilogue reads lpA/lpB instead of recomputing logp.
// ---------------------------------------------------------------------------
#define HALO 14
#define NKROW 196
#define LQK 136          // 128 + 8 pad (272 B rows)
#define LSS 204          // S f32 row stride: (4*204)%32 = 16 -> free 2-way
#define NIT 13
#define NITEMS (64*KK2)  // 3136

__global__ __launch_bounds__(256, 3) void attn_mfma_lp(
        const unsigned short* __restrict__ qk,
        const uint4* __restrict__ lpA,
        const unsigned short* __restrict__ lpB,
        float* __restrict__ out)
{
    __shared__ __align__(16) unsigned char smem[53312];   // K 53312 B; S 52224 B
    unsigned short* Ks = (unsigned short*)smem;
    float* Ss = (float*)smem;

    const int bid = blockIdx.x;
    const int spatial = (bid & 7) * 256 + (bid >> 3);
    const int tw = spatial & 15;
    const int th = (spatial >> 4) & 15;
    const int bg = spatial >> 8;          // 0..7
    const int b = bg >> 2, g = bg & 3;

    const int tid = threadIdx.x;
    const int lane = tid & 63;
    const int wm = tid >> 6;

    const int h0 = th * 8, w0 = tw * 8;
    const int hb = min(max(h0 - RR, 0), HH - KS);
    const int wb = min(max(w0 - RR, 0), WW - KS);

    // ---- stage K halo for head g ----
    uint4 kb[NIT];
    int jrow[NIT], ccol[NIT];
#pragma unroll
    for (int p = 0; p < NIT; ++p) {
        int o = tid + p * 256;
        int jj = o >> 4, c = o & 15;
        int jr = min(jj, NKROW - 1);
        int hj = min(hb + jr / HALO, HH - 1);
        int wj = min(wb + jr % HALO, WW - 1);
        kb[p] = *(const uint4*)(qk + ((size_t)((b * HH + hj) * WW + wj)) * GN
                                   + CC + g * HD + c * 8);
        jrow[p] = jr; ccol[p] = c;
    }

    const int pl_q = wm * 16 + (lane & 15);
    const size_t qrow = ((size_t)(b * HH + h0 + (pl_q >> 3)) * WW + w0 + (pl_q & 7)) * GN;
    const int kof8 = (lane >> 4) * 8;
    bf16x8 aq[4];
#pragma unroll
    for (int ks = 0; ks < 4; ++ks)
        aq[ks] = *(const bf16x8*)(qk + qrow + g * HD + ks * 32 + kof8);

#pragma unroll
    for (int p = 0; p < NIT; ++p)
        *(uint4*)&Ks[jrow[p] * LQK + ccol[p] * 8] = kb[p];
    __syncthreads();

    // ---- MFMA S[64][196+clamp] ----
    __builtin_amdgcn_s_setprio(1);
    f32x4 svals[NIT];
#pragma unroll
    for (int nt = 0; nt < NIT; ++nt) {
        int rB = min(nt * 16 + (lane & 15), NKROW - 1);
        f32x4 sacc = (f32x4){0.f, 0.f, 0.f, 0.f};
#pragma unroll
        for (int ks = 0; ks < 4; ++ks) {
            bf16x8 bk = *(const bf16x8*)&Ks[rB * LQK + ks * 32 + kof8];
            sacc = __builtin_amdgcn_mfma_f32_16x16x32_bf16(aq[ks], bk, sacc, 0, 0, 0);
        }
        svals[nt] = sacc;
    }
    __builtin_amdgcn_s_setprio(0);
    __syncthreads();

    // ---- S -> LDS ----
#pragma unroll
    for (int nt = 0; nt < NIT; ++nt)
#pragma unroll
        for (int r = 0; r < 4; ++r) {
            int qr = wm * 16 + (lane >> 4) * 4 + r;
            Ss[qr * LSS + nt * 16 + (lane & 15)] = svals[nt][r];
        }
    __syncthreads();

    // ---- readout + preloaded logp + 9 NT writes per item ----
    const size_t plane = (size_t)HH * WW * KK2;
#pragma unroll
    for (int rr = 0; rr < NIT; ++rr) {
        int it = tid + rr * 256;
        if (it < NITEMS) {
            int pl = it / KK2, ki = it % KK2;
            int h = h0 + (pl >> 3), w = w0 + (pl & 7);
            int dh = ki / KS, dw = ki % KS;
            int hj = min(max(h - RR, 0), HH - KS) + dh;
            int wj = min(max(w - RR, 0), WW - KS) + dw;
            int j = (hj - hb) * HALO + (wj - wb);
            float dot = Ss[pl * LSS + j];
            int pix = (b * HH + h) * WW + w;
            size_t item = (size_t)pix * KK2 + ki;

            uint4 va = lpA[item];
            unsigned int vb = lpB[item];
            float lp[NSI];
            lp[0] = bflo(va.x); lp[1] = bfhi(va.x);
            lp[2] = bflo(va.y); lp[3] = bfhi(va.y);
            lp[4] = bflo(va.z); lp[5] = bfhi(va.z);
            lp[6] = bflo(va.w); lp[7] = bfhi(va.w);
            lp[8] = bflo(vb);

            size_t inner = (size_t)(h * WW + w) * KK2 + ki;
#pragma unroll
            for (int si = 0; si < NSI; ++si)
                __builtin_nontemporal_store(sout(dot + lp[si]),
                    &out[((size_t)((b * NH + g) * NSI + si)) * plane + inner]);
        }
    }
}

// ---------------------------------------------------------------------------
// Kernel 2b (middle path): round-13 attn with inline logp (known-good).
// ---------------------------------------------------------------------------
__global__ __launch_bounds__(256, 3) void attn_mfma_full(
        const unsigned short* __restrict__ qk,
        const float* __restrict__ sims,
        const int*   __restrict__ sinds,
        float* __restrict__ out)
{
    __shared__ __align__(16) unsigned char smem[53312];
    unsigned short* Ks = (unsigned short*)smem;
    float* Ss = (float*)smem;

    const int bid = blockIdx.x;
    const int spatial = (bid & 7) * 256 + (bid >> 3);
    const int tw = spatial & 15;
    const int th = (spatial >> 4) & 15;
    const int bg = spatial >> 8;
    const int b = bg >> 2, g = bg & 3;

    const int tid = threadIdx.x;
    const int lane = tid & 63;
    const int wm = tid >> 6;

    const int h0 = th * 8, w0 = tw * 8;
    const int hb = min(max(h0 - RR, 0), HH - KS);
    const int wb = min(max(w0 - RR, 0), WW - KS);

    uint4 kb[NIT];
    int jrow[NIT], ccol[NIT];
#pragma unroll
    for (int p = 0; p < NIT; ++p) {
        int o = tid + p * 256;
        int jj = o >> 4, c = o & 15;
        int jr = min(jj, NKROW - 1);
        int hj = min(hb + jr / HALO, HH - 1);
        int wj = min(wb + jr % HALO, WW - 1);
        kb[p] = *(const uint4*)(qk + ((size_t)((b * HH + hj) * WW + wj)) * GN
                                   + CC + g * HD + c * 8);
        jrow[p] = jr; ccol[p] = c;
    }

    const int pl_q = wm * 16 + (lane & 15);
    const size_t qrow = ((size_t)(b * HH + h0 + (pl_q >> 3)) * WW + w0 + (pl_q & 7)) * GN;
    const int kof8 = (lane >> 4) * 8;
    bf16x8 aq[4];
#pragma unroll
    for (int ks = 0; ks < 4; ++ks)
        aq[ks] = *(const bf16x8*)(qk + qrow + g * HD + ks * 32 + kof8);

#pragma unroll
    for (int p = 0; p < NIT; ++p)
        *(uint4*)&Ks[jrow[p] * LQK + ccol[p] * 8] = kb[p];
    __syncthreads();

    __builtin_amdgcn_s_setprio(1);
    f32x4 svals[NIT];
#pragma unroll
    for (int nt = 0; nt < NIT; ++nt) {
        int rB = min(nt * 16 + (lane & 15), NKROW - 1);
        f32x4 sacc = (f32x4){0.f, 0.f, 0.f, 0.f};
#pragma unroll
        for (int ks = 0; ks < 4; ++ks) {
            bf16x8 bk = *(const bf16x8*)&Ks[rB * LQK + ks * 32 + kof8];
            sacc = __builtin_amdgcn_mfma_f32_16x16x32_bf16(aq[ks], bk, sacc, 0, 0, 0);
        }
        svals[nt] = sacc;
    }
    __builtin_amdgcn_s_setprio(0);
    __syncthreads();

#pragma unroll
    for (int nt = 0; nt < NIT; ++nt)
#pragma unroll
        for (int r = 0; r < 4; ++r) {
            int qr = wm * 16 + (lane >> 4) * 4 + r;
            Ss[qr * LSS + nt * 16 + (lane & 15)] = svals[nt][r];
        }
    __syncthreads();

    const size_t plane = (size_t)HH * WW * KK2;
#pragma unroll
    for (int rr = 0; rr < NIT; ++rr) {
        int it = tid + rr * 256;
        if (it < NITEMS) {
            int pl = it / KK2, ki = it % KK2;
            int h = h0 + (pl >> 3), w = w0 + (pl & 7);
            int dh = ki / KS, dw = ki % KS;
            int hj = min(max(h - RR, 0), HH - KS) + dh;
            int wj = min(max(w - RR, 0), WW - KS) + dw;
            int j = (hj - hb) * HALO + (wj - wb);
            float dot = Ss[pl * LSS + j];
            int pix = (b * HH + h) * WW + w;
            int pj  = (b * HH + hj) * WW + wj;

            int sid[NSI], sjd[NSI]; float sjm[NSI];
            const int*   sip = sinds + (size_t)pix * NSI;
            const int*   sjp = sinds + (size_t)pj * NSI;
            const float* smp = sims + (size_t)pj * NSI;
#pragma unroll
            for (int m = 0; m < NSI; ++m) { sid[m] = sip[m]; sjd[m] = sjp[m]; sjm[m] = smp[m]; }

            size_t inner = (size_t)(h * WW + w) * KK2 + ki;
#pragma unroll
            for (int si = 0; si < NSI; ++si) {
                float p = 0.f;
#pragma unroll
                for (int m = 0; m < NSI; ++m) p += (sjd[m] == sid[si]) ? sjm[m] : 0.f;
                float lpv = (p > 0.f) ? __logf(fmaxf(p, 1e-30f)) : NEG_HUGE;
                __builtin_nontemporal_store(sout(dot + lpv),
                    &out[((size_t)((b * NH + g) * NSI + si)) * plane + inner]);
            }
        }
    }
}

// ---------------------------------------------------------------------------
// Zero-workspace fallback (round-5 fused VALU path).
// ---------------------------------------------------------------------------
#define FT 8
#define FH 14
#define FNP (FT*FT)
#define FNJ (FH*FH)
#define FDH 64
#define KPAD 68
#define FNITEM (FNP*KK2)
#define FNR 13

__global__ __launch_bounds__(256) void fused_attn(
        const float* __restrict__ x, const float* __restrict__ sims,
        const int* __restrict__ sinds, const float* __restrict__ Wm,
        const float* __restrict__ bias, float* __restrict__ out)
{
    __shared__ unsigned short kt[FNJ][KPAD];
    __shared__ unsigned short qt[FNP][KPAD];

    const int tw = blockIdx.x, th = blockIdx.y;
    const int b = blockIdx.z >> 2, g = blockIdx.z & 3;
    const int tid = threadIdx.x;
    const int hb = min(max(th * FT - RR, 0), HH - KS);
    const int wb = min(max(tw * FT - RR, 0), WW - KS);

    float dacc[FNR];
#pragma unroll
    for (int r = 0; r < FNR; ++r) dacc[r] = 0.f;

    for (int ph = 0; ph < 2; ++ph) {
        const int kcol0 = CC + g * HD + ph * FDH;
        const int qcol0 = g * HD + ph * FDH;

        for (int o = tid; o < FNJ * FDH; o += 256) {
            int j = o >> 6, dd = o & 63;
            int hj = min(hb + j / FH, HH - 1), wj = min(wb + j % FH, WW - 1);
            const float* xr = x + ((size_t)(b * HH + hj) * WW + wj) * CC;
            int col = kcol0 + dd;
            float acc = bias[col];
            for (int c = 0; c < CC; c += 4) {
                float4 xv = *(const float4*)(xr + c);
                acc += xv.x * Wm[(size_t)c * GN + col]
                     + xv.y * Wm[(size_t)(c + 1) * GN + col]
                     + xv.z * Wm[(size_t)(c + 2) * GN + col]
                     + xv.w * Wm[(size_t)(c + 3) * GN + col];
            }
            kt[j][dd] = f2bf(acc);
        }
        for (int o = tid; o < FNP * FDH; o += 256) {
            int i = o >> 6, dd = o & 63;
            int h = th * FT + (i >> 3), w = tw * FT + (i & 7);
            const float* xr = x + ((size_t)(b * HH + h) * WW + w) * CC;
            int col = qcol0 + dd;
            float acc = bias[col];
            for (int c = 0; c < CC; c += 4) {
                float4 xv = *(const float4*)(xr + c);
                acc += xv.x * Wm[(size_t)c * GN + col]
                     + xv.y * Wm[(size_t)(c + 1) * GN + col]
                     + xv.z * Wm[(size_t)(c + 2) * GN + col]
                     + xv.w * Wm[(size_t)(c + 3) * GN + col];
            }
            qt[i][dd] = f2bf(acc);
        }
        __syncthreads();

#pragma unroll
        for (int r = 0; r < FNR; ++r) {
            int it = tid + r * 256;
            if (it < FNITEM) {
                int pl = it / KK2, ki = it % KK2;
                int h = th * FT + (pl >> 3), w = tw * FT + (pl & 7);
                int dh = ki / KS, dw = ki % KS;
                int hj = min(max(h - RR, 0), HH - KS) + dh;
                int wj = min(max(w - RR, 0), WW - KS) + dw;
                int j = (hj - hb) * FH + (wj - wb);
                const unsigned int* qr = (const unsigned int*)&qt[pl][0];
                const unsigned int* kr = (const unsigned int*)&kt[j][0];
                float a = 0.f;
#pragma unroll 8
                for (int d = 0; d < FDH / 2; ++d) {
                    unsigned int qv = qr[d], kv = kr[d];
                    a += bflo(qv) * bflo(kv) + bfhi(qv) * bfhi(kv);
                }
                dacc[r] += a;
            }
        }
        __syncthreads();
    }

    const size_t plane = (size_t)HH * WW * KK2;
#pragma unroll
    for (int r = 0; r < FNR; ++r) {
        int it = tid + r * 256;
        if (it < FNITEM) {
            int pl = it / KK2, ki = it % KK2;
            int h = th * FT + (pl >> 3), w = tw * FT + (pl & 7);
            int dh = ki / KS, dw = ki % KS;
            int hj = min(max(h - RR, 0), HH - KS) + dh;
            int wj = min(max(w - RR, 0), WW - KS) + dw;
            int pix = (b * HH + h) * WW + w;
            int pj  = (b * HH + hj) * WW + wj;

            int sid[NSI], sjd[NSI]; float sjm[NSI];
            const int*   sip = sinds + (size_t)pix * NSI;
            const int*   sjp = sinds + (size_t)pj * NSI;
            const float* smp = sims + (size_t)pj * NSI;
#pragma unroll
            for (int m = 0; m < NSI; ++m) { sid[m] = sip[m]; sjd[m] = sjp[m]; sjm[m] = smp[m]; }

            const size_t inner = (size_t)(h * WW + w) * KK2 + ki;
#pragma unroll
            for (int si = 0; si < NSI; ++si) {
                float p = 0.f;
#pragma unroll
                for (int m = 0; m < NSI; ++m) p += (sjd[m] == sid[si]) ? sjm[m] : 0.f;
                float lp = (p > 0.f) ? __logf(fmaxf(p, 1e-30f)) : NEG_HUGE;
                out[((size_t)((b * NH + g) * NSI + si)) * plane + inner] =
                    sout(dacc[r] + lp);
            }
        }
    }
}

// ---------------------------------------------------------------------------
extern "C" void kernel_launch(void* const* d_in, const int* in_sizes, int n_in,
                              void* d_out, int out_size, void* d_ws, size_t ws_size,
                              hipStream_t stream) {
    const float* x     = (const float*)d_in[0];
    const float* sims  = (const float*)d_in[1];
    const int*   sinds = (const int*)d_in[2];
    const float* W_qk  = (const float*)d_in[3];
    const float* b_qk  = (const float*)d_in[4];
    float* out = (float*)d_out;

    const size_t qk_bytes = (size_t)GM * GN * sizeof(unsigned short);      // 67,108,864
    const size_t wt_bytes = (size_t)GN * GK * sizeof(unsigned short);      //  1,048,576
    const size_t xb_bytes = (size_t)GM * GK * sizeof(unsigned short);      // 33,554,432
    const size_t lpA_bytes = (size_t)NITEM_ALL * sizeof(uint4);            // 25,690,112
    const size_t lpB_bytes = (size_t)NITEM_ALL * sizeof(unsigned short);   //  3,211,264

    if (ws_size >= qk_bytes + wt_bytes + xb_bytes + lpA_bytes + lpB_bytes) {
        unsigned short* qk = (unsigned short*)d_ws;
        unsigned short* Wt = (unsigned short*)((char*)d_ws + qk_bytes);
        unsigned short* xb = (unsigned short*)((char*)d_ws + qk_bytes + wt_bytes);
        uint4* lpA = (uint4*)((char*)d_ws + qk_bytes + wt_bytes + xb_bytes);
        unsigned short* lpB = (unsigned short*)((char*)d_ws + qk_bytes + wt_bytes
                                                + xb_bytes + lpA_bytes);

        const int nxc = 8192, nwt = 2048, nlp = (NITEM_ALL + 255) / 256;   // 6272
        prep<<<nxc + nwt + nlp, 256, 0, stream>>>(x, xb, W_qk, Wt,
                                                  sims, sinds, lpA, lpB, nxc, nwt);
        qk_gemm_async<<<2048, 256, 0, stream>>>(xb, Wt, b_qk, qk);
        attn_mfma_lp<<<2048, 256, 0, stream>>>(qk, lpA, lpB, out);
    } else if (ws_size >= qk_bytes + wt_bytes) {
        unsigned short* qk = (unsigned short*)d_ws;
        unsigned short* Wt = (unsigned short*)((char*)d_ws + qk_bytes);

        prep<<<2048, 256, 0, stream>>>(x, nullptr, W_qk, Wt,
                                       nullptr, nullptr, nullptr, nullptr, 0, 2048);
        dim3 ggrid(GM / TBM, GN / TBN);
        qk_gemm_conv<<<ggrid, 256, 0, stream>>>(x, Wt, b_qk, qk);
        attn_mfma_full<<<2048, 256, 0, stream>>>(qk, sims, sinds, out);
    } else {
        dim3 fgrid(WW / FT, HH / FT, BATCH * NH);
        fused_attn<<<fgrid, 256, 0, stream>>>(x, sims, sinds, W_qk, b_qk, out);
    }
}